// Round 8
// baseline (314.424 us; speedup 1.0000x reference)
//
#include <hip/hip_runtime.h>
#include <hip/hip_bf16.h>
#include <math.h>

#define NV 64
#define ND 64
#define NTOK 8192
#define LN_EPS 1e-5f

typedef __attribute__((ext_vector_type(8))) short s8v;    // 8 bf16 = 4 VGPR
typedef __attribute__((ext_vector_type(4))) float f4v;    // MFMA C/D
typedef __attribute__((ext_vector_type(4))) int   i4v;

__device__ __forceinline__ float sigm_f(float x) { return 1.f / (1.f + __expf(-x)); }
__device__ __forceinline__ float elu_f(float x)  { return x > 0.f ? x : (__expf(x) - 1.f); }

__device__ __forceinline__ float bf16_to_f(unsigned short s) {
    union { unsigned int u; float f; } c; c.u = ((unsigned int)s) << 16;
    return c.f;
}
// 1-op round-to-nearest (ties away)
__device__ __forceinline__ unsigned short bf16_rn(float f) {
    union { float f; unsigned int u; } c; c.f = f;
    return (unsigned short)((c.u + 0x8000u) >> 16);
}

// ---------------- Prepack: all weight transposes via LDS tiles (coalesced R+W)
__global__ __launch_bounds__(256) void vsn_prepack(
    const float* __restrict__ W2, const float* __restrict__ Wg,
    const float* __restrict__ Wn1, const float* __restrict__ Wns,
    short* __restrict__ w2b, short* __restrict__ wgb,
    __hip_bfloat16* __restrict__ wct)
{
    __shared__ float T[64][65];
    const int b = blockIdx.x, t = threadIdx.x;

    if (b < 64) {
        const float* src = W2 + (size_t)b * 4096;
        short* dst = w2b + (size_t)b * 4096;
        #pragma unroll
        for (int pass = 0; pass < 2; ++pass) {
            #pragma unroll
            for (int i = 0; i < 16; ++i) {
                int id = i * 256 + t;
                T[id & 63][id >> 6] = src[id];
            }
            __syncthreads();
            #pragma unroll
            for (int i = 0; i < 16; ++i) {
                int id = i * 256 + t;
                dst[id] = (short)bf16_rn(T[id >> 6][id & 63]);
            }
            __syncthreads();
            src = Wg + (size_t)b * 4096;
            dst = wgb + (size_t)b * 4096;
        }
    } else {
        int tb = b - 64;
        int half = tb >> 6, kt = tb & 63;
        const float* src = (half == 0 ? Wn1 : Wns) + (size_t)(kt * 64) * 64;
        #pragma unroll
        for (int i = 0; i < 16; ++i) {
            int id = i * 256 + t;
            T[id & 63][id >> 6] = src[id];
        }
        __syncthreads();
        #pragma unroll
        for (int i = 0; i < 16; ++i) {
            int id = i * 256 + t;
            int n = id >> 6, r = id & 63;
            wct[(size_t)(half * 64 + n) * 4096 + kt * 64 + r] =
                __float2bfloat16(T[n][r]);
        }
    }
}

// ---------------- Stage 1: per-variable GRN + LN via bf16 MFMA -> stacked bf16
// (unchanged from round 7)
__global__ __launch_bounds__(256) void vsn_stage1(
    const float* __restrict__ x,
    const float* __restrict__ W1, const float* __restrict__ b1,
    const short* __restrict__ w2b, const short* __restrict__ wgb,
    const float* __restrict__ b2, const float* __restrict__ bg,
    const float* __restrict__ Wsk, const float* __restrict__ bsk,
    const float* __restrict__ gamma, const float* __restrict__ beta,
    __hip_bfloat16* __restrict__ stb)
{
    const int t = threadIdx.x;
    const int wave = t >> 6, lane = t & 63;
    const int m16 = lane & 15, quad = lane >> 4;
    const int tile0 = blockIdx.x * 32;
    const int v = blockIdx.y * 4 + wave;

    __shared__ float xs[4][32];
    __shared__ __align__(16) unsigned short h2s[4][32][72];

    if (lane < 32) xs[wave][lane] = x[(size_t)(tile0 + lane) * NV + v];

    s8v a[2][2];
    #pragma unroll
    for (int kt = 0; kt < 2; ++kt) {
        float w1k[8], b1k[8];
        *(float4*)&w1k[0] = *(const float4*)(W1 + v * 64 + kt * 32 + quad * 8);
        *(float4*)&w1k[4] = *(const float4*)(W1 + v * 64 + kt * 32 + quad * 8 + 4);
        *(float4*)&b1k[0] = *(const float4*)(b1 + v * 64 + kt * 32 + quad * 8);
        *(float4*)&b1k[4] = *(const float4*)(b1 + v * 64 + kt * 32 + quad * 8 + 4);
        #pragma unroll
        for (int mi = 0; mi < 2; ++mi) {
            float xv = xs[wave][mi * 16 + m16];
            float h[8];
            #pragma unroll
            for (int j = 0; j < 8; ++j) h[j] = elu_f(fmaf(xv, w1k[j], b1k[j]));
            i4v av;
            #pragma unroll
            for (int p = 0; p < 4; ++p) {
                unsigned int u0 = __float_as_uint(h[2 * p]);
                unsigned int u1 = __float_as_uint(h[2 * p + 1]);
                av[p] = (int)((u1 & 0xffff0000u) | (u0 >> 16));
            }
            a[mi][kt] = *(s8v*)&av;
        }
    }

    f4v hacc[2][4];
    #pragma unroll
    for (int mi = 0; mi < 2; ++mi)
        #pragma unroll
        for (int ni = 0; ni < 4; ++ni) hacc[mi][ni] = (f4v){0.f, 0.f, 0.f, 0.f};

    const size_t wb = (size_t)v * 4096;
    #pragma unroll
    for (int ni = 0; ni < 4; ++ni)
        #pragma unroll
        for (int kt = 0; kt < 2; ++kt) {
            s8v bh = *(const s8v*)(w2b + wb + (size_t)(ni * 16 + m16) * 64 + kt * 32 + quad * 8);
            #pragma unroll
            for (int mi = 0; mi < 2; ++mi)
                hacc[mi][ni] = __builtin_amdgcn_mfma_f32_16x16x32_bf16(a[mi][kt], bh, hacc[mi][ni], 0, 0, 0);
        }
    {
        float b2d[4];
        #pragma unroll
        for (int ni = 0; ni < 4; ++ni) b2d[ni] = b2[v * 64 + ni * 16 + m16];
        #pragma unroll
        for (int mi = 0; mi < 2; ++mi)
            #pragma unroll
            for (int ni = 0; ni < 4; ++ni)
                #pragma unroll
                for (int r = 0; r < 4; ++r) hacc[mi][ni][r] += b2d[ni];
    }

    #pragma unroll
    for (int mi = 0; mi < 2; ++mi)
        #pragma unroll
        for (int ni = 0; ni < 4; ++ni)
            #pragma unroll
            for (int r = 0; r < 4; ++r)
                h2s[wave][mi * 16 + quad * 4 + r][ni * 16 + m16] =
                    (unsigned short)(__float_as_uint(hacc[mi][ni][r]) >> 16);

    s8v c[2][2];
    #pragma unroll
    for (int mi = 0; mi < 2; ++mi)
        #pragma unroll
        for (int kt = 0; kt < 2; ++kt)
            c[mi][kt] = *(const s8v*)&h2s[wave][mi * 16 + m16][kt * 32 + quad * 8];

    f4v gacc[2][4];
    #pragma unroll
    for (int mi = 0; mi < 2; ++mi)
        #pragma unroll
        for (int ni = 0; ni < 4; ++ni) gacc[mi][ni] = (f4v){0.f, 0.f, 0.f, 0.f};
    #pragma unroll
    for (int ni = 0; ni < 4; ++ni)
        #pragma unroll
        for (int kt = 0; kt < 2; ++kt) {
            s8v bh = *(const s8v*)(wgb + wb + (size_t)(ni * 16 + m16) * 64 + kt * 32 + quad * 8);
            #pragma unroll
            for (int mi = 0; mi < 2; ++mi)
                gacc[mi][ni] = __builtin_amdgcn_mfma_f32_16x16x32_bf16(c[mi][kt], bh, gacc[mi][ni], 0, 0, 0);
        }

    {
        float bgd[4], wskd[4], bskd[4];
        #pragma unroll
        for (int ni = 0; ni < 4; ++ni) {
            int d = v * 64 + ni * 16 + m16;
            bgd[ni] = bg[d]; wskd[ni] = Wsk[d]; bskd[ni] = bsk[d];
        }
        float xtok[2][4];
        #pragma unroll
        for (int mi = 0; mi < 2; ++mi)
            #pragma unroll
            for (int r = 0; r < 4; ++r) xtok[mi][r] = xs[wave][mi * 16 + quad * 4 + r];
        #pragma unroll
        for (int mi = 0; mi < 2; ++mi)
            #pragma unroll
            for (int ni = 0; ni < 4; ++ni)
                #pragma unroll
                for (int r = 0; r < 4; ++r) {
                    float g = sigm_f(gacc[mi][ni][r] + bgd[ni]);
                    gacc[mi][ni][r] = fmaf(xtok[mi][r], wskd[ni], bskd[ni]) + g * hacc[mi][ni][r];
                }
    }

    {
        float gamd[4], betd[4];
        #pragma unroll
        for (int ni = 0; ni < 4; ++ni) {
            int d = v * 64 + ni * 16 + m16;
            gamd[ni] = gamma[d]; betd[ni] = beta[d];
        }
        #pragma unroll
        for (int mi = 0; mi < 2; ++mi)
            #pragma unroll
            for (int r = 0; r < 4; ++r) {
                float s0 = gacc[mi][0][r], s1 = gacc[mi][1][r], s2 = gacc[mi][2][r], s3 = gacc[mi][3][r];
                float sum = s0 + s1 + s2 + s3;
                float sq  = s0 * s0 + s1 * s1 + s2 * s2 + s3 * s3;
                #pragma unroll
                for (int m = 1; m < 16; m <<= 1) { sum += __shfl_xor(sum, m); sq += __shfl_xor(sq, m); }
                float mu  = sum * 0.015625f;
                float var = sq * 0.015625f - mu * mu;
                float rs  = rsqrtf(var + LN_EPS);
                size_t base = (size_t)(tile0 + mi * 16 + quad * 4 + r) * 4096 + (size_t)v * 64 + m16;
                #pragma unroll
                for (int ni = 0; ni < 4; ++ni)
                    stb[base + ni * 16] = __hip_bfloat16_raw{
                        bf16_rn((gacc[mi][ni][r] - mu) * rs * gamd[ni] + betd[ni])};
            }
    }
}

// ---------------- Fused Stage 2 v2: 1024 blocks x 8 tokens x 8 waves (512 thr).
// Wave w: nh = w&1 (64 cols), ks = w>>1 (K-slice 1024). M=16 MFMA tile with
// duplicated A rows (row = tok0 + (m16&7)): C rows 8..15 are discards, A-load
// line count halves. 4 blocks/CU -> 32 waves/CU for latency hiding.
__global__ __launch_bounds__(512) void vsn_stage2(
    const __hip_bfloat16* __restrict__ stb,   // [8192][4096]
    const __hip_bfloat16* __restrict__ wct,   // [128][4096]
    const float* __restrict__ bn1,
    const float* __restrict__ Wn2, const float* __restrict__ bn2,
    const float* __restrict__ Wng, const float* __restrict__ bng,
    const float* __restrict__ bns,
    const float* __restrict__ ngamma, const float* __restrict__ nbeta,
    float* __restrict__ out)
{
    const int t = threadIdx.x;
    const int w = t >> 6, lane = t & 63;
    const int m16 = lane & 15, quad = lane >> 4;
    const int nh = w & 1, ks = w >> 1;
    const int tok0 = blockIdx.x * 8;

    // P[2][3][64][17] fp32 = 26112 B reduce buffer; tail arrays overlay it.
    __shared__ __align__(16) float P[2][3][64][17];
    __shared__ __align__(16) float S[8][132];
    float (*hw1)[64] = (float(*)[64])&P[0][0][0][0];
    float (*skw)[64] = (float(*)[64])(&P[0][0][0][0] + 512);
    float (*hw2)[64] = (float(*)[64])(&P[0][0][0][0] + 1024);
    float (*s2m)[64] = (float(*)[64])(&P[0][0][0][0] + 1536);
    float (*wgt)[64] = (float(*)[64])(&P[0][0][0][0] + 2048);

    const short* A  = (const short*)stb;
    const short* Bw = (const short*)wct;
    const int k0 = ks * 1024;

    // ---- K-loop
    f4v acc[4];
    #pragma unroll
    for (int nj = 0; nj < 4; ++nj) acc[nj] = (f4v){0.f, 0.f, 0.f, 0.f};

    const short* arow = A  + (size_t)(tok0 + (m16 & 7)) * 4096 + k0 + quad * 8;
    const short* brow = Bw + (size_t)(nh * 64 + m16) * 4096 + k0 + quad * 8;

    #pragma unroll 4
    for (int kk = 0; kk < 1024; kk += 32) {
        s8v a0 = *(const s8v*)(arow + kk);
        s8v b[4];
        #pragma unroll
        for (int nj = 0; nj < 4; ++nj)
            b[nj] = *(const s8v*)(brow + (size_t)nj * 16 * 4096 + kk);
        #pragma unroll
        for (int nj = 0; nj < 4; ++nj)
            acc[nj] = __builtin_amdgcn_mfma_f32_16x16x32_bf16(a0, b[nj], acc[nj], 0, 0, 0);
    }

    // ---- reduce 4 K-slices per n-half: ks 1..3 publish, ks 0 accumulates
    if (ks >= 1) {
        float* p = &P[nh][ks - 1][lane][0];
        #pragma unroll
        for (int nj = 0; nj < 4; ++nj)
            #pragma unroll
            for (int r = 0; r < 4; ++r) p[nj * 4 + r] = acc[nj][r];
    }
    __syncthreads();
    if (ks == 0) {
        #pragma unroll
        for (int s = 0; s < 3; ++s) {
            const float* p = &P[nh][s][lane][0];
            #pragma unroll
            for (int nj = 0; nj < 4; ++nj)
                #pragma unroll
                for (int r = 0; r < 4; ++r) acc[nj][r] += p[nj * 4 + r];
        }
        if (quad < 2) {   // rows 0..7 valid
            #pragma unroll
            for (int nj = 0; nj < 4; ++nj)
                #pragma unroll
                for (int r = 0; r < 4; ++r)
                    S[quad * 4 + r][nh * 64 + nj * 16 + m16] = acc[nj][r];
        }
    }
    __syncthreads();

    // ---- tail step 1: hw1 = elu(S[:, :64]+bn1), skw = S[:, 64:]+bns  (P dead)
    {
        int m = t >> 6, j = t & 63;
        hw1[m][j] = elu_f(S[m][j] + bn1[j]);
        skw[m][j] = S[m][64 + j] + bns[j];
    }
    __syncthreads();

    // ---- step 2: hw2 = hw1 @ Wn2 + bn2
    {
        int m = t >> 6, j = t & 63;
        float a2 = bn2[j];
        #pragma unroll
        for (int k4 = 0; k4 < 16; ++k4) {
            float4 h = *(const float4*)&hw1[m][k4 * 4];
            a2 += h.x * Wn2[(k4*4+0)*64+j] + h.y * Wn2[(k4*4+1)*64+j]
                + h.z * Wn2[(k4*4+2)*64+j] + h.w * Wn2[(k4*4+3)*64+j];
        }
        hw2[m][j] = a2;
    }
    __syncthreads();

    // ---- step 3: gw = sigm(hw2 @ Wng + bng); s2 = skw + gw*hw2
    {
        int m = t >> 6, vv = t & 63;
        float a3 = bng[vv];
        #pragma unroll
        for (int k4 = 0; k4 < 16; ++k4) {
            float4 h = *(const float4*)&hw2[m][k4 * 4];
            a3 += h.x * Wng[(k4*4+0)*64+vv] + h.y * Wng[(k4*4+1)*64+vv]
                + h.z * Wng[(k4*4+2)*64+vv] + h.w * Wng[(k4*4+3)*64+vv];
        }
        float gw = sigm_f(a3);
        s2m[m][vv] = skw[m][vv] + gw * hw2[m][vv];
    }
    __syncthreads();

    // ---- step 4: LN over v + softmax; 8 tokens x 16 lanes = 128 threads
    if (t < 128) {
        int tt = t >> 4, l = t & 15;
        float z[4]; float sum = 0.f, sq = 0.f;
        #pragma unroll
        for (int i = 0; i < 4; ++i) { z[i] = s2m[tt][l + 16 * i]; sum += z[i]; sq += z[i] * z[i]; }
        #pragma unroll
        for (int m = 1; m < 16; m <<= 1) { sum += __shfl_xor(sum, m); sq += __shfl_xor(sq, m); }
        float mu  = sum * 0.015625f;
        float var = sq * 0.015625f - mu * mu;
        float rs  = rsqrtf(var + LN_EPS);
        float ln[4]; float mx = -1e30f;
        #pragma unroll
        for (int i = 0; i < 4; ++i) {
            ln[i] = (z[i] - mu) * rs * ngamma[l + 16 * i] + nbeta[l + 16 * i];
            mx = fmaxf(mx, ln[i]);
        }
        #pragma unroll
        for (int m = 1; m < 16; m <<= 1) mx = fmaxf(mx, __shfl_xor(mx, m));
        float es = 0.f; float ev[4];
        #pragma unroll
        for (int i = 0; i < 4; ++i) { ev[i] = __expf(ln[i] - mx); es += ev[i]; }
        #pragma unroll
        for (int m = 1; m < 16; m <<= 1) es += __shfl_xor(es, m);
        float inv = 1.f / es;
        #pragma unroll
        for (int i = 0; i < 4; ++i) wgt[tt][l + 16 * i] = ev[i] * inv;
    }
    __syncthreads();

    // ---- step 5: weighted sum; wave w -> token tok0 + w (L2/L3-warm rows)
    {
        const int vloc = lane >> 3, d8 = (lane & 7) * 8;
        const short* sp = A + (size_t)(tok0 + w) * 4096 + d8;
        float a8[8];
        #pragma unroll
        for (int j = 0; j < 8; ++j) a8[j] = 0.f;
        #pragma unroll
        for (int vc = 0; vc < 8; ++vc) {
            int v = vc * 8 + vloc;
            s8v r = *(const s8v*)(sp + v * 64);
            float wv = wgt[w][v];
            #pragma unroll
            for (int j = 0; j < 8; ++j)
                a8[j] = fmaf(wv, bf16_to_f((unsigned short)r[j]), a8[j]);
        }
        #pragma unroll
        for (int m = 8; m <= 32; m <<= 1)
            #pragma unroll
            for (int j = 0; j < 8; ++j) a8[j] += __shfl_xor(a8[j], m);
        if (lane < 8) {
            float* op = out + (size_t)(tok0 + w) * 64 + lane * 8;
            *(float4*)op       = make_float4(a8[0], a8[1], a8[2], a8[3]);
            *(float4*)(op + 4) = make_float4(a8[4], a8[5], a8[6], a8[7]);
        }
    }
}

extern "C" void kernel_launch(void* const* d_in, const int* in_sizes, int n_in,
                              void* d_out, int out_size, void* d_ws, size_t ws_size,
                              hipStream_t stream) {
    const float* x     = (const float*)d_in[0];
    const float* W1    = (const float*)d_in[1];
    const float* b1    = (const float*)d_in[2];
    const float* W2    = (const float*)d_in[3];
    const float* b2    = (const float*)d_in[4];
    const float* Wg    = (const float*)d_in[5];
    const float* bg    = (const float*)d_in[6];
    const float* Wsk   = (const float*)d_in[7];
    const float* bsk   = (const float*)d_in[8];
    const float* gamma = (const float*)d_in[9];
    const float* beta  = (const float*)d_in[10];
    const float* Wn1   = (const float*)d_in[11];
    const float* bn1   = (const float*)d_in[12];
    const float* Wn2   = (const float*)d_in[13];
    const float* bn2   = (const float*)d_in[14];
    const float* Wng   = (const float*)d_in[15];
    const float* bng   = (const float*)d_in[16];
    const float* Wns   = (const float*)d_in[17];
    const float* bns   = (const float*)d_in[18];
    const float* ngam  = (const float*)d_in[19];
    const float* nbet  = (const float*)d_in[20];

    char* ws = (char*)d_ws;
    __hip_bfloat16* stb = (__hip_bfloat16*)ws;                   // 64 MiB
    __hip_bfloat16* wct = (__hip_bfloat16*)(ws + (64u << 20));   // 1 MiB
    short* w2b = (short*)(ws + (65u << 20));                     // 512 KiB each
    short* wgb = w2b + 262144;
    float* outp = (float*)d_out;

    vsn_prepack<<<dim3(192), 256, 0, stream>>>(W2, Wg, Wn1, Wns, w2b, wgb, wct);
    vsn_stage1<<<dim3(NTOK / 32, 16), 256, 0, stream>>>(
        x, W1, b1, w2b, wgb, b2, bg, Wsk, bsk, gamma, beta, stb);
    vsn_stage2<<<dim3(NTOK / 8), 512, 0, stream>>>(
        stb, wct, bn1, Wn2, bn2, Wng, bng, bns, ngam, nbet, outp);
}

// Round 9
// 230.919 us; speedup vs baseline: 1.3616x; 1.3616x over previous
//
#include <hip/hip_runtime.h>
#include <hip/hip_bf16.h>
#include <math.h>

#define NV 64
#define ND 64
#define NTOK 8192
#define LN_EPS 1e-5f
#define KSPLIT 8
#define KRANGE (4096 / KSPLIT)   // 512

typedef __attribute__((ext_vector_type(8))) short s8v;    // 8 bf16 = 4 VGPR
typedef __attribute__((ext_vector_type(4))) float f4v;    // MFMA C/D
typedef __attribute__((ext_vector_type(4))) int   i4v;

__device__ __forceinline__ float sigm_f(float x) { return 1.f / (1.f + __expf(-x)); }
__device__ __forceinline__ float elu_f(float x)  { return x > 0.f ? x : (__expf(x) - 1.f); }

__device__ __forceinline__ float bf16_to_f(unsigned short s) {
    union { unsigned int u; float f; } c; c.u = ((unsigned int)s) << 16;
    return c.f;
}
// 1-op round-to-nearest (ties away)
__device__ __forceinline__ unsigned short bf16_rn(float f) {
    union { float f; unsigned int u; } c; c.f = f;
    return (unsigned short)((c.u + 0x8000u) >> 16);
}

// ---------------- Prepack: all weight transposes via LDS tiles (coalesced R+W)
// [round-7 verified]
__global__ __launch_bounds__(256) void vsn_prepack(
    const float* __restrict__ W2, const float* __restrict__ Wg,
    const float* __restrict__ Wn1, const float* __restrict__ Wns,
    short* __restrict__ w2b, short* __restrict__ wgb,
    __hip_bfloat16* __restrict__ wct)
{
    __shared__ float T[64][65];
    const int b = blockIdx.x, t = threadIdx.x;

    if (b < 64) {
        const float* src = W2 + (size_t)b * 4096;
        short* dst = w2b + (size_t)b * 4096;
        #pragma unroll
        for (int pass = 0; pass < 2; ++pass) {
            #pragma unroll
            for (int i = 0; i < 16; ++i) {
                int id = i * 256 + t;
                T[id & 63][id >> 6] = src[id];
            }
            __syncthreads();
            #pragma unroll
            for (int i = 0; i < 16; ++i) {
                int id = i * 256 + t;
                dst[id] = (short)bf16_rn(T[id >> 6][id & 63]);
            }
            __syncthreads();
            src = Wg + (size_t)b * 4096;
            dst = wgb + (size_t)b * 4096;
        }
    } else {
        int tb = b - 64;
        int half = tb >> 6, kt = tb & 63;
        const float* src = (half == 0 ? Wn1 : Wns) + (size_t)(kt * 64) * 64;
        #pragma unroll
        for (int i = 0; i < 16; ++i) {
            int id = i * 256 + t;
            T[id & 63][id >> 6] = src[id];
        }
        __syncthreads();
        #pragma unroll
        for (int i = 0; i < 16; ++i) {
            int id = i * 256 + t;
            int n = id >> 6, r = id & 63;
            wct[(size_t)(half * 64 + n) * 4096 + kt * 64 + r] =
                __float2bfloat16(T[n][r]);
        }
    }
}

// ---------------- Stage 1: per-variable GRN + LN via bf16 MFMA -> stacked bf16
// [round-7 verified, absmax 5.86e-3]
__global__ __launch_bounds__(256) void vsn_stage1(
    const float* __restrict__ x,
    const float* __restrict__ W1, const float* __restrict__ b1,
    const short* __restrict__ w2b, const short* __restrict__ wgb,
    const float* __restrict__ b2, const float* __restrict__ bg,
    const float* __restrict__ Wsk, const float* __restrict__ bsk,
    const float* __restrict__ gamma, const float* __restrict__ beta,
    __hip_bfloat16* __restrict__ stb)
{
    const int t = threadIdx.x;
    const int wave = t >> 6, lane = t & 63;
    const int m16 = lane & 15, quad = lane >> 4;
    const int tile0 = blockIdx.x * 32;
    const int v = blockIdx.y * 4 + wave;

    __shared__ float xs[4][32];
    __shared__ __align__(16) unsigned short h2s[4][32][72];

    if (lane < 32) xs[wave][lane] = x[(size_t)(tile0 + lane) * NV + v];

    s8v a[2][2];
    #pragma unroll
    for (int kt = 0; kt < 2; ++kt) {
        float w1k[8], b1k[8];
        *(float4*)&w1k[0] = *(const float4*)(W1 + v * 64 + kt * 32 + quad * 8);
        *(float4*)&w1k[4] = *(const float4*)(W1 + v * 64 + kt * 32 + quad * 8 + 4);
        *(float4*)&b1k[0] = *(const float4*)(b1 + v * 64 + kt * 32 + quad * 8);
        *(float4*)&b1k[4] = *(const float4*)(b1 + v * 64 + kt * 32 + quad * 8 + 4);
        #pragma unroll
        for (int mi = 0; mi < 2; ++mi) {
            float xv = xs[wave][mi * 16 + m16];
            float h[8];
            #pragma unroll
            for (int j = 0; j < 8; ++j) h[j] = elu_f(fmaf(xv, w1k[j], b1k[j]));
            i4v av;
            #pragma unroll
            for (int p = 0; p < 4; ++p) {
                unsigned int u0 = __float_as_uint(h[2 * p]);
                unsigned int u1 = __float_as_uint(h[2 * p + 1]);
                av[p] = (int)((u1 & 0xffff0000u) | (u0 >> 16));
            }
            a[mi][kt] = *(s8v*)&av;
        }
    }

    f4v hacc[2][4];
    #pragma unroll
    for (int mi = 0; mi < 2; ++mi)
        #pragma unroll
        for (int ni = 0; ni < 4; ++ni) hacc[mi][ni] = (f4v){0.f, 0.f, 0.f, 0.f};

    const size_t wb = (size_t)v * 4096;
    #pragma unroll
    for (int ni = 0; ni < 4; ++ni)
        #pragma unroll
        for (int kt = 0; kt < 2; ++kt) {
            s8v bh = *(const s8v*)(w2b + wb + (size_t)(ni * 16 + m16) * 64 + kt * 32 + quad * 8);
            #pragma unroll
            for (int mi = 0; mi < 2; ++mi)
                hacc[mi][ni] = __builtin_amdgcn_mfma_f32_16x16x32_bf16(a[mi][kt], bh, hacc[mi][ni], 0, 0, 0);
        }
    {
        float b2d[4];
        #pragma unroll
        for (int ni = 0; ni < 4; ++ni) b2d[ni] = b2[v * 64 + ni * 16 + m16];
        #pragma unroll
        for (int mi = 0; mi < 2; ++mi)
            #pragma unroll
            for (int ni = 0; ni < 4; ++ni)
                #pragma unroll
                for (int r = 0; r < 4; ++r) hacc[mi][ni][r] += b2d[ni];
    }

    #pragma unroll
    for (int mi = 0; mi < 2; ++mi)
        #pragma unroll
        for (int ni = 0; ni < 4; ++ni)
            #pragma unroll
            for (int r = 0; r < 4; ++r)
                h2s[wave][mi * 16 + quad * 4 + r][ni * 16 + m16] =
                    (unsigned short)(__float_as_uint(hacc[mi][ni][r]) >> 16);

    s8v c[2][2];
    #pragma unroll
    for (int mi = 0; mi < 2; ++mi)
        #pragma unroll
        for (int kt = 0; kt < 2; ++kt)
            c[mi][kt] = *(const s8v*)&h2s[wave][mi * 16 + m16][kt * 32 + quad * 8];

    f4v gacc[2][4];
    #pragma unroll
    for (int mi = 0; mi < 2; ++mi)
        #pragma unroll
        for (int ni = 0; ni < 4; ++ni) gacc[mi][ni] = (f4v){0.f, 0.f, 0.f, 0.f};
    #pragma unroll
    for (int ni = 0; ni < 4; ++ni)
        #pragma unroll
        for (int kt = 0; kt < 2; ++kt) {
            s8v bh = *(const s8v*)(wgb + wb + (size_t)(ni * 16 + m16) * 64 + kt * 32 + quad * 8);
            #pragma unroll
            for (int mi = 0; mi < 2; ++mi)
                gacc[mi][ni] = __builtin_amdgcn_mfma_f32_16x16x32_bf16(c[mi][kt], bh, gacc[mi][ni], 0, 0, 0);
        }

    {
        float bgd[4], wskd[4], bskd[4];
        #pragma unroll
        for (int ni = 0; ni < 4; ++ni) {
            int d = v * 64 + ni * 16 + m16;
            bgd[ni] = bg[d]; wskd[ni] = Wsk[d]; bskd[ni] = bsk[d];
        }
        float xtok[2][4];
        #pragma unroll
        for (int mi = 0; mi < 2; ++mi)
            #pragma unroll
            for (int r = 0; r < 4; ++r) xtok[mi][r] = xs[wave][mi * 16 + quad * 4 + r];
        #pragma unroll
        for (int mi = 0; mi < 2; ++mi)
            #pragma unroll
            for (int ni = 0; ni < 4; ++ni)
                #pragma unroll
                for (int r = 0; r < 4; ++r) {
                    float g = sigm_f(gacc[mi][ni][r] + bgd[ni]);
                    gacc[mi][ni][r] = fmaf(xtok[mi][r], wskd[ni], bskd[ni]) + g * hacc[mi][ni][r];
                }
    }

    {
        float gamd[4], betd[4];
        #pragma unroll
        for (int ni = 0; ni < 4; ++ni) {
            int d = v * 64 + ni * 16 + m16;
            gamd[ni] = gamma[d]; betd[ni] = beta[d];
        }
        #pragma unroll
        for (int mi = 0; mi < 2; ++mi)
            #pragma unroll
            for (int r = 0; r < 4; ++r) {
                float s0 = gacc[mi][0][r], s1 = gacc[mi][1][r], s2 = gacc[mi][2][r], s3 = gacc[mi][3][r];
                float sum = s0 + s1 + s2 + s3;
                float sq  = s0 * s0 + s1 * s1 + s2 * s2 + s3 * s3;
                #pragma unroll
                for (int m = 1; m < 16; m <<= 1) { sum += __shfl_xor(sum, m); sq += __shfl_xor(sq, m); }
                float mu  = sum * 0.015625f;
                float var = sq * 0.015625f - mu * mu;
                float rs  = rsqrtf(var + LN_EPS);
                size_t base = (size_t)(tile0 + mi * 16 + quad * 4 + r) * 4096 + (size_t)v * 64 + m16;
                #pragma unroll
                for (int ni = 0; ni < 4; ++ni)
                    stb[base + ni * 16] = __hip_bfloat16_raw{
                        bf16_rn((gacc[mi][ni][r] - mu) * rs * gamd[ni] + betd[ni])};
            }
    }
}

// ---------------- Stage 2a: part[s][tok][0:128] = flat @ [Wn1|Wns] over K-range s
// [round-5 verified] grid (128 M-tiles, 8 K-splits), block 256 (4 waves), no LDS.
__global__ __launch_bounds__(256) void vsn_stage2a(
    const __hip_bfloat16* __restrict__ stb,   // [8192][4096]
    const __hip_bfloat16* __restrict__ wct,   // [128][4096]
    float* __restrict__ part)
{
    const int t = threadIdx.x;
    const int wave = t >> 6, lane = t & 63;
    const int tok0 = blockIdx.x * 64;
    const int s = blockIdx.y;
    const int k0 = s * KRANGE;
    const int m16 = lane & 15, quad = lane >> 4;
    const int n0 = wave * 32;

    const short* A  = (const short*)stb;
    const short* Bw = (const short*)wct;

    f4v acc[4][2];
    #pragma unroll
    for (int i = 0; i < 4; ++i)
        #pragma unroll
        for (int j = 0; j < 2; ++j)
            acc[i][j] = (f4v){0.f, 0.f, 0.f, 0.f};

    const short* arow = A  + (size_t)(tok0 + m16) * 4096 + quad * 8;
    const short* brow = Bw + (size_t)(n0 + m16) * 4096 + quad * 8;

    for (int k = k0; k < k0 + KRANGE; k += 32) {
        s8v a[4], b[2];
        #pragma unroll
        for (int i = 0; i < 4; ++i)
            a[i] = *(const s8v*)(arow + (size_t)i * 16 * 4096 + k);
        #pragma unroll
        for (int j = 0; j < 2; ++j)
            b[j] = *(const s8v*)(brow + (size_t)j * 16 * 4096 + k);
        #pragma unroll
        for (int i = 0; i < 4; ++i)
            #pragma unroll
            for (int j = 0; j < 2; ++j)
                acc[i][j] = __builtin_amdgcn_mfma_f32_16x16x32_bf16(a[i], b[j], acc[i][j], 0, 0, 0);
    }

    #pragma unroll
    for (int i = 0; i < 4; ++i)
        #pragma unroll
        for (int j = 0; j < 2; ++j)
            #pragma unroll
            for (int r = 0; r < 4; ++r)
                part[((size_t)s * NTOK + tok0 + i * 16 + quad * 4 + r) * 128
                     + n0 + j * 16 + m16] = acc[i][j][r];
}

// ---------------- Stage 2b: reduce partials, tail GRN, softmax, vectorized weighted sum
// [round-5 verified] 8 tokens per block -> 1024 blocks, 256 threads.
__global__ __launch_bounds__(256) void vsn_stage2b(
    const __hip_bfloat16* __restrict__ stb, const float* __restrict__ part,
    const float* __restrict__ bn1,
    const float* __restrict__ Wn2, const float* __restrict__ bn2,
    const float* __restrict__ Wng, const float* __restrict__ bng,
    const float* __restrict__ bns,
    const float* __restrict__ ngamma, const float* __restrict__ nbeta,
    float* __restrict__ out)
{
    const int t = threadIdx.x;
    const int tok0 = blockIdx.x * 8;

    __shared__ __align__(16) float hw1_s[8][64];
    __shared__ float skw_s[8][64];
    __shared__ __align__(16) float hw2_s[8][64];
    __shared__ float s2_s[8][64];
    __shared__ float w_s[8][64];

    #pragma unroll
    for (int i = 0; i < 2; ++i) {
        int oidx = i * 256 + t;
        int tt = oidx >> 6, jj = oidx & 63;
        size_t rb = (size_t)(tok0 + tt) * 128;
        float p1 = 0.f, ps = 0.f;
        #pragma unroll
        for (int s = 0; s < KSPLIT; ++s) {
            p1 += part[(size_t)s * NTOK * 128 + rb + jj];
            ps += part[(size_t)s * NTOK * 128 + rb + 64 + jj];
        }
        hw1_s[tt][jj] = elu_f(p1 + bn1[jj]);
        skw_s[tt][jj] = ps + bns[jj];
    }
    __syncthreads();

    #pragma unroll
    for (int i = 0; i < 2; ++i) {
        int oidx = i * 256 + t;
        int tt = oidx >> 6, jj = oidx & 63;
        float acc = bn2[jj];
        #pragma unroll
        for (int k4 = 0; k4 < 16; ++k4) {
            float4 h = *(const float4*)&hw1_s[tt][k4 * 4];
            acc += h.x * Wn2[(k4*4+0)*64+jj] + h.y * Wn2[(k4*4+1)*64+jj]
                 + h.z * Wn2[(k4*4+2)*64+jj] + h.w * Wn2[(k4*4+3)*64+jj];
        }
        hw2_s[tt][jj] = acc;
    }
    __syncthreads();

    #pragma unroll
    for (int i = 0; i < 2; ++i) {
        int oidx = i * 256 + t;
        int tt = oidx >> 6, vv = oidx & 63;
        float acc = bng[vv];
        #pragma unroll
        for (int k4 = 0; k4 < 16; ++k4) {
            float4 h = *(const float4*)&hw2_s[tt][k4 * 4];
            acc += h.x * Wng[(k4*4+0)*64+vv] + h.y * Wng[(k4*4+1)*64+vv]
                 + h.z * Wng[(k4*4+2)*64+vv] + h.w * Wng[(k4*4+3)*64+vv];
        }
        float gw = sigm_f(acc);
        s2_s[tt][vv] = skw_s[tt][vv] + gw * hw2_s[tt][vv];
    }
    __syncthreads();

    if (t < 128) {
        int tt = t >> 4, l = t & 15;
        float z[4]; float sum = 0.f, sq = 0.f;
        #pragma unroll
        for (int i = 0; i < 4; ++i) { z[i] = s2_s[tt][l + 16 * i]; sum += z[i]; sq += z[i] * z[i]; }
        #pragma unroll
        for (int m = 1; m < 16; m <<= 1) { sum += __shfl_xor(sum, m); sq += __shfl_xor(sq, m); }
        float mu  = sum * 0.015625f;
        float var = sq * 0.015625f - mu * mu;
        float rs  = rsqrtf(var + LN_EPS);
        float ln[4]; float mx = -1e30f;
        #pragma unroll
        for (int i = 0; i < 4; ++i) {
            ln[i] = (z[i] - mu) * rs * ngamma[l + 16 * i] + nbeta[l + 16 * i];
            mx = fmaxf(mx, ln[i]);
        }
        #pragma unroll
        for (int m = 1; m < 16; m <<= 1) mx = fmaxf(mx, __shfl_xor(mx, m));
        float es = 0.f; float ev[4];
        #pragma unroll
        for (int i = 0; i < 4; ++i) { ev[i] = __expf(ln[i] - mx); es += ev[i]; }
        #pragma unroll
        for (int m = 1; m < 16; m <<= 1) es += __shfl_xor(es, m);
        float inv = 1.f / es;
        #pragma unroll
        for (int i = 0; i < 4; ++i) w_s[tt][l + 16 * i] = ev[i] * inv;
    }
    __syncthreads();

    {
        const int lane = t & 63, wv = t >> 6;
        const int vloc = lane >> 3, d8 = (lane & 7) * 8;
        const short* s0 = (const short*)stb + (size_t)(tok0 + wv * 2) * 4096 + d8;
        const short* s1 = s0 + 4096;
        float acc0[8], acc1[8];
        #pragma unroll
        for (int j = 0; j < 8; ++j) { acc0[j] = 0.f; acc1[j] = 0.f; }
        #pragma unroll
        for (int vc = 0; vc < 8; ++vc) {
            int v = vc * 8 + vloc;
            s8v r0 = *(const s8v*)(s0 + v * 64);
            s8v r1 = *(const s8v*)(s1 + v * 64);
            float w0 = w_s[wv * 2][v], w1 = w_s[wv * 2 + 1][v];
            #pragma unroll
            for (int j = 0; j < 8; ++j) {
                acc0[j] = fmaf(w0, bf16_to_f((unsigned short)r0[j]), acc0[j]);
                acc1[j] = fmaf(w1, bf16_to_f((unsigned short)r1[j]), acc1[j]);
            }
        }
        #pragma unroll
        for (int m = 8; m <= 32; m <<= 1)
            #pragma unroll
            for (int j = 0; j < 8; ++j) {
                acc0[j] += __shfl_xor(acc0[j], m);
                acc1[j] += __shfl_xor(acc1[j], m);
            }
        if (lane < 8) {
            float* op = out + (size_t)(tok0 + wv * 2) * 64 + lane * 8;
            *(float4*)op       = make_float4(acc0[0], acc0[1], acc0[2], acc0[3]);
            *(float4*)(op + 4) = make_float4(acc0[4], acc0[5], acc0[6], acc0[7]);
            op += 64;
            *(float4*)op       = make_float4(acc1[0], acc1[1], acc1[2], acc1[3]);
            *(float4*)(op + 4) = make_float4(acc1[4], acc1[5], acc1[6], acc1[7]);
        }
    }
}

extern "C" void kernel_launch(void* const* d_in, const int* in_sizes, int n_in,
                              void* d_out, int out_size, void* d_ws, size_t ws_size,
                              hipStream_t stream) {
    const float* x     = (const float*)d_in[0];
    const float* W1    = (const float*)d_in[1];
    const float* b1    = (const float*)d_in[2];
    const float* W2    = (const float*)d_in[3];
    const float* b2    = (const float*)d_in[4];
    const float* Wg    = (const float*)d_in[5];
    const float* bg    = (const float*)d_in[6];
    const float* Wsk   = (const float*)d_in[7];
    const float* bsk   = (const float*)d_in[8];
    const float* gamma = (const float*)d_in[9];
    const float* beta  = (const float*)d_in[10];
    const float* Wn1   = (const float*)d_in[11];
    const float* bn1   = (const float*)d_in[12];
    const float* Wn2   = (const float*)d_in[13];
    const float* bn2   = (const float*)d_in[14];
    const float* Wng   = (const float*)d_in[15];
    const float* bng   = (const float*)d_in[16];
    const float* Wns   = (const float*)d_in[17];
    const float* bns   = (const float*)d_in[18];
    const float* ngam  = (const float*)d_in[19];
    const float* nbet  = (const float*)d_in[20];

    char* ws = (char*)d_ws;
    __hip_bfloat16* stb = (__hip_bfloat16*)ws;                   // 64 MiB
    __hip_bfloat16* wct = (__hip_bfloat16*)(ws + (64u << 20));   // 1 MiB
    float* part = (float*)(ws + (65u << 20));                    // 32 MiB (8 x 8192 x 128)
    short* w2b = (short*)(ws + (97u << 20));                     // 512 KiB each
    short* wgb = w2b + 262144;
    float* outp = (float*)d_out;

    vsn_prepack<<<dim3(192), 256, 0, stream>>>(W2, Wg, Wn1, Wns, w2b, wgb, wct);
    vsn_stage1<<<dim3(NTOK / 32, 16), 256, 0, stream>>>(
        x, W1, b1, w2b, wgb, b2, bg, Wsk, bsk, gamma, beta, stb);
    vsn_stage2a<<<dim3(NTOK / 64, KSPLIT), 256, 0, stream>>>(stb, wct, part);
    vsn_stage2b<<<dim3(NTOK / 8), 256, 0, stream>>>(
        stb, part, bn1, Wn2, bn2, Wng, bng, bns, ngam, nbet, outp);
}

// Round 10
// 228.461 us; speedup vs baseline: 1.3763x; 1.0108x over previous
//
#include <hip/hip_runtime.h>
#include <hip/hip_bf16.h>
#include <math.h>

#define NV 64
#define ND 64
#define NTOK 8192
#define LN_EPS 1e-5f
#define KSPLIT 8
#define KRANGE (4096 / KSPLIT)   // 512

typedef __attribute__((ext_vector_type(8))) short s8v;    // 8 bf16 = 4 VGPR
typedef __attribute__((ext_vector_type(4))) float f4v;    // MFMA C/D
typedef __attribute__((ext_vector_type(4))) int   i4v;

__device__ __forceinline__ float sigm_f(float x) { return 1.f / (1.f + __expf(-x)); }
__device__ __forceinline__ float elu_f(float x)  { return x > 0.f ? x : (__expf(x) - 1.f); }

__device__ __forceinline__ float bf16_to_f(unsigned short s) {
    union { unsigned int u; float f; } c; c.u = ((unsigned int)s) << 16;
    return c.f;
}
// 1-op round-to-nearest (ties away)
__device__ __forceinline__ unsigned short bf16_rn(float f) {
    union { float f; unsigned int u; } c; c.f = f;
    return (unsigned short)((c.u + 0x8000u) >> 16);
}

// ---------------- Prepack: all weight transposes via LDS tiles (coalesced R+W)
// [round-7 verified]
__global__ __launch_bounds__(256) void vsn_prepack(
    const float* __restrict__ W2, const float* __restrict__ Wg,
    const float* __restrict__ Wn1, const float* __restrict__ Wns,
    short* __restrict__ w2b, short* __restrict__ wgb,
    __hip_bfloat16* __restrict__ wct)
{
    __shared__ float T[64][65];
    const int b = blockIdx.x, t = threadIdx.x;

    if (b < 64) {
        const float* src = W2 + (size_t)b * 4096;
        short* dst = w2b + (size_t)b * 4096;
        #pragma unroll
        for (int pass = 0; pass < 2; ++pass) {
            #pragma unroll
            for (int i = 0; i < 16; ++i) {
                int id = i * 256 + t;
                T[id & 63][id >> 6] = src[id];
            }
            __syncthreads();
            #pragma unroll
            for (int i = 0; i < 16; ++i) {
                int id = i * 256 + t;
                dst[id] = (short)bf16_rn(T[id >> 6][id & 63]);
            }
            __syncthreads();
            src = Wg + (size_t)b * 4096;
            dst = wgb + (size_t)b * 4096;
        }
    } else {
        int tb = b - 64;
        int half = tb >> 6, kt = tb & 63;
        const float* src = (half == 0 ? Wn1 : Wns) + (size_t)(kt * 64) * 64;
        #pragma unroll
        for (int i = 0; i < 16; ++i) {
            int id = i * 256 + t;
            T[id & 63][id >> 6] = src[id];
        }
        __syncthreads();
        #pragma unroll
        for (int i = 0; i < 16; ++i) {
            int id = i * 256 + t;
            int n = id >> 6, r = id & 63;
            wct[(size_t)(half * 64 + n) * 4096 + kt * 64 + r] =
                __float2bfloat16(T[n][r]);
        }
    }
}

// ---------------- Stage 1: per-variable GRN + LN via bf16 MFMA -> stacked bf16
// [round-7 verified, absmax 5.86e-3; unchanged]
__global__ __launch_bounds__(256) void vsn_stage1(
    const float* __restrict__ x,
    const float* __restrict__ W1, const float* __restrict__ b1,
    const short* __restrict__ w2b, const short* __restrict__ wgb,
    const float* __restrict__ b2, const float* __restrict__ bg,
    const float* __restrict__ Wsk, const float* __restrict__ bsk,
    const float* __restrict__ gamma, const float* __restrict__ beta,
    __hip_bfloat16* __restrict__ stb)
{
    const int t = threadIdx.x;
    const int wave = t >> 6, lane = t & 63;
    const int m16 = lane & 15, quad = lane >> 4;
    const int tile0 = blockIdx.x * 32;
    const int v = blockIdx.y * 4 + wave;

    __shared__ float xs[4][32];
    __shared__ __align__(16) unsigned short h2s[4][32][72];

    if (lane < 32) xs[wave][lane] = x[(size_t)(tile0 + lane) * NV + v];

    s8v a[2][2];
    #pragma unroll
    for (int kt = 0; kt < 2; ++kt) {
        float w1k[8], b1k[8];
        *(float4*)&w1k[0] = *(const float4*)(W1 + v * 64 + kt * 32 + quad * 8);
        *(float4*)&w1k[4] = *(const float4*)(W1 + v * 64 + kt * 32 + quad * 8 + 4);
        *(float4*)&b1k[0] = *(const float4*)(b1 + v * 64 + kt * 32 + quad * 8);
        *(float4*)&b1k[4] = *(const float4*)(b1 + v * 64 + kt * 32 + quad * 8 + 4);
        #pragma unroll
        for (int mi = 0; mi < 2; ++mi) {
            float xv = xs[wave][mi * 16 + m16];
            float h[8];
            #pragma unroll
            for (int j = 0; j < 8; ++j) h[j] = elu_f(fmaf(xv, w1k[j], b1k[j]));
            i4v av;
            #pragma unroll
            for (int p = 0; p < 4; ++p) {
                unsigned int u0 = __float_as_uint(h[2 * p]);
                unsigned int u1 = __float_as_uint(h[2 * p + 1]);
                av[p] = (int)((u1 & 0xffff0000u) | (u0 >> 16));
            }
            a[mi][kt] = *(s8v*)&av;
        }
    }

    f4v hacc[2][4];
    #pragma unroll
    for (int mi = 0; mi < 2; ++mi)
        #pragma unroll
        for (int ni = 0; ni < 4; ++ni) hacc[mi][ni] = (f4v){0.f, 0.f, 0.f, 0.f};

    const size_t wb = (size_t)v * 4096;
    #pragma unroll
    for (int ni = 0; ni < 4; ++ni)
        #pragma unroll
        for (int kt = 0; kt < 2; ++kt) {
            s8v bh = *(const s8v*)(w2b + wb + (size_t)(ni * 16 + m16) * 64 + kt * 32 + quad * 8);
            #pragma unroll
            for (int mi = 0; mi < 2; ++mi)
                hacc[mi][ni] = __builtin_amdgcn_mfma_f32_16x16x32_bf16(a[mi][kt], bh, hacc[mi][ni], 0, 0, 0);
        }
    {
        float b2d[4];
        #pragma unroll
        for (int ni = 0; ni < 4; ++ni) b2d[ni] = b2[v * 64 + ni * 16 + m16];
        #pragma unroll
        for (int mi = 0; mi < 2; ++mi)
            #pragma unroll
            for (int ni = 0; ni < 4; ++ni)
                #pragma unroll
                for (int r = 0; r < 4; ++r) hacc[mi][ni][r] += b2d[ni];
    }

    #pragma unroll
    for (int mi = 0; mi < 2; ++mi)
        #pragma unroll
        for (int ni = 0; ni < 4; ++ni)
            #pragma unroll
            for (int r = 0; r < 4; ++r)
                h2s[wave][mi * 16 + quad * 4 + r][ni * 16 + m16] =
                    (unsigned short)(__float_as_uint(hacc[mi][ni][r]) >> 16);

    s8v c[2][2];
    #pragma unroll
    for (int mi = 0; mi < 2; ++mi)
        #pragma unroll
        for (int kt = 0; kt < 2; ++kt)
            c[mi][kt] = *(const s8v*)&h2s[wave][mi * 16 + m16][kt * 32 + quad * 8];

    f4v gacc[2][4];
    #pragma unroll
    for (int mi = 0; mi < 2; ++mi)
        #pragma unroll
        for (int ni = 0; ni < 4; ++ni) gacc[mi][ni] = (f4v){0.f, 0.f, 0.f, 0.f};
    #pragma unroll
    for (int ni = 0; ni < 4; ++ni)
        #pragma unroll
        for (int kt = 0; kt < 2; ++kt) {
            s8v bh = *(const s8v*)(wgb + wb + (size_t)(ni * 16 + m16) * 64 + kt * 32 + quad * 8);
            #pragma unroll
            for (int mi = 0; mi < 2; ++mi)
                gacc[mi][ni] = __builtin_amdgcn_mfma_f32_16x16x32_bf16(c[mi][kt], bh, gacc[mi][ni], 0, 0, 0);
        }

    {
        float bgd[4], wskd[4], bskd[4];
        #pragma unroll
        for (int ni = 0; ni < 4; ++ni) {
            int d = v * 64 + ni * 16 + m16;
            bgd[ni] = bg[d]; wskd[ni] = Wsk[d]; bskd[ni] = bsk[d];
        }
        float xtok[2][4];
        #pragma unroll
        for (int mi = 0; mi < 2; ++mi)
            #pragma unroll
            for (int r = 0; r < 4; ++r) xtok[mi][r] = xs[wave][mi * 16 + quad * 4 + r];
        #pragma unroll
        for (int mi = 0; mi < 2; ++mi)
            #pragma unroll
            for (int ni = 0; ni < 4; ++ni)
                #pragma unroll
                for (int r = 0; r < 4; ++r) {
                    float g = sigm_f(gacc[mi][ni][r] + bgd[ni]);
                    gacc[mi][ni][r] = fmaf(xtok[mi][r], wskd[ni], bskd[ni]) + g * hacc[mi][ni][r];
                }
    }

    {
        float gamd[4], betd[4];
        #pragma unroll
        for (int ni = 0; ni < 4; ++ni) {
            int d = v * 64 + ni * 16 + m16;
            gamd[ni] = gamma[d]; betd[ni] = beta[d];
        }
        #pragma unroll
        for (int mi = 0; mi < 2; ++mi)
            #pragma unroll
            for (int r = 0; r < 4; ++r) {
                float s0 = gacc[mi][0][r], s1 = gacc[mi][1][r], s2 = gacc[mi][2][r], s3 = gacc[mi][3][r];
                float sum = s0 + s1 + s2 + s3;
                float sq  = s0 * s0 + s1 * s1 + s2 * s2 + s3 * s3;
                #pragma unroll
                for (int m = 1; m < 16; m <<= 1) { sum += __shfl_xor(sum, m); sq += __shfl_xor(sq, m); }
                float mu  = sum * 0.015625f;
                float var = sq * 0.015625f - mu * mu;
                float rs  = rsqrtf(var + LN_EPS);
                size_t base = (size_t)(tile0 + mi * 16 + quad * 4 + r) * 4096 + (size_t)v * 64 + m16;
                #pragma unroll
                for (int ni = 0; ni < 4; ++ni)
                    stb[base + ni * 16] = __hip_bfloat16_raw{
                        bf16_rn((gacc[mi][ni][r] - mu) * rs * gamd[ni] + betd[ni])};
            }
    }
}

// ---------------- Stage 2a: part[tok][s][0:128] = flat @ [Wn1|Wns] over K-range s
// 512-thread blocks: 128 tokens (2 M-tiles x 4 n-waves); B slices L1-shared by
// 8 waves, B L2 traffic halved vs 64-tok blocks. grid (64, KSPLIT), 16 waves/CU.
__global__ __launch_bounds__(512) void vsn_stage2a(
    const __hip_bfloat16* __restrict__ stb,   // [8192][4096]
    const __hip_bfloat16* __restrict__ wct,   // [128][4096]
    float* __restrict__ part)                 // [8192][KSPLIT][128]
{
    const int t = threadIdx.x;
    const int wave = t >> 6, lane = t & 63;
    const int mtile = wave >> 2;
    const int n0 = (wave & 3) * 32;
    const int tok0 = blockIdx.x * 128 + mtile * 64;
    const int s = blockIdx.y;
    const int k0 = s * KRANGE;
    const int m16 = lane & 15, quad = lane >> 4;

    const short* A  = (const short*)stb;
    const short* Bw = (const short*)wct;

    f4v acc[4][2];
    #pragma unroll
    for (int i = 0; i < 4; ++i)
        #pragma unroll
        for (int j = 0; j < 2; ++j)
            acc[i][j] = (f4v){0.f, 0.f, 0.f, 0.f};

    const short* arow = A  + (size_t)(tok0 + m16) * 4096 + quad * 8;
    const short* brow = Bw + (size_t)(n0 + m16) * 4096 + quad * 8;

    for (int k = k0; k < k0 + KRANGE; k += 32) {
        s8v a[4], b[2];
        #pragma unroll
        for (int i = 0; i < 4; ++i)
            a[i] = *(const s8v*)(arow + (size_t)i * 16 * 4096 + k);
        #pragma unroll
        for (int j = 0; j < 2; ++j)
            b[j] = *(const s8v*)(brow + (size_t)j * 16 * 4096 + k);
        #pragma unroll
        for (int i = 0; i < 4; ++i)
            #pragma unroll
            for (int j = 0; j < 2; ++j)
                acc[i][j] = __builtin_amdgcn_mfma_f32_16x16x32_bf16(a[i], b[j], acc[i][j], 0, 0, 0);
    }

    #pragma unroll
    for (int i = 0; i < 4; ++i)
        #pragma unroll
        for (int j = 0; j < 2; ++j)
            #pragma unroll
            for (int r = 0; r < 4; ++r)
                part[((size_t)(tok0 + i * 16 + quad * 4 + r)) * (KSPLIT * 128)
                     + s * 128 + n0 + j * 16 + m16] = acc[i][j][r];
}

// ---------------- Stage 2b: contiguous part reduce, tail GRN, softmax, weighted sum
// 8 tokens per block -> 1024 blocks, 256 threads (4 waves; wave = 2 tokens).
__global__ __launch_bounds__(256) void vsn_stage2b(
    const __hip_bfloat16* __restrict__ stb, const float* __restrict__ part,
    const float* __restrict__ bn1,
    const float* __restrict__ Wn2, const float* __restrict__ bn2,
    const float* __restrict__ Wng, const float* __restrict__ bng,
    const float* __restrict__ bns,
    const float* __restrict__ ngamma, const float* __restrict__ nbeta,
    float* __restrict__ out)
{
    const int t = threadIdx.x;
    const int tok0 = blockIdx.x * 8;
    const int lane = t & 63, wv = t >> 6;

    __shared__ __align__(16) float hw1_s[8][64];
    __shared__ __align__(16) float skw_s[8][64];
    __shared__ __align__(16) float hw2_s[8][64];
    __shared__ float s2_s[8][64];
    __shared__ float w_s[8][64];

    // ---- phase 1: reduce part[tok][0:8][0:128] with contiguous f4 wave-loads.
    // lane: s-pair member = lane>>5, f4 slot = lane&31 (j = 4*(lane&31)).
    #pragma unroll
    for (int tk = 0; tk < 2; ++tk) {
        int tl = wv * 2 + tk;
        const float* pr = part + (size_t)(tok0 + tl) * (KSPLIT * 128)
                        + (lane >> 5) * 128 + (lane & 31) * 4;
        float4 a0 = *(const float4*)(pr);
        float4 a1 = *(const float4*)(pr + 256);
        float4 a2 = *(const float4*)(pr + 512);
        float4 a3 = *(const float4*)(pr + 768);
        float tv[4];
        tv[0] = a0.x + a1.x + a2.x + a3.x;
        tv[1] = a0.y + a1.y + a2.y + a3.y;
        tv[2] = a0.z + a1.z + a2.z + a3.z;
        tv[3] = a0.w + a1.w + a2.w + a3.w;
        #pragma unroll
        for (int c = 0; c < 4; ++c) tv[c] += __shfl_xor(tv[c], 32);
        if (lane < 16) {
            int j0 = lane * 4;
            float4 bb = *(const float4*)(bn1 + j0);
            hw1_s[tl][j0 + 0] = elu_f(tv[0] + bb.x);
            hw1_s[tl][j0 + 1] = elu_f(tv[1] + bb.y);
            hw1_s[tl][j0 + 2] = elu_f(tv[2] + bb.z);
            hw1_s[tl][j0 + 3] = elu_f(tv[3] + bb.w);
        } else if (lane < 32) {
            int j0 = (lane - 16) * 4;
            float4 bb = *(const float4*)(bns + j0);
            skw_s[tl][j0 + 0] = tv[0] + bb.x;
            skw_s[tl][j0 + 1] = tv[1] + bb.y;
            skw_s[tl][j0 + 2] = tv[2] + bb.z;
            skw_s[tl][j0 + 3] = tv[3] + bb.w;
        }
    }
    __syncthreads();

    // ---- hw2 = hw1 @ Wn2 + bn2
    #pragma unroll
    for (int i = 0; i < 2; ++i) {
        int oidx = i * 256 + t;
        int tt = oidx >> 6, jj = oidx & 63;
        float acc = bn2[jj];
        #pragma unroll
        for (int k4 = 0; k4 < 16; ++k4) {
            float4 h = *(const float4*)&hw1_s[tt][k4 * 4];
            acc += h.x * Wn2[(k4*4+0)*64+jj] + h.y * Wn2[(k4*4+1)*64+jj]
                 + h.z * Wn2[(k4*4+2)*64+jj] + h.w * Wn2[(k4*4+3)*64+jj];
        }
        hw2_s[tt][jj] = acc;
    }
    __syncthreads();

    // ---- gw = sigmoid(hw2 @ Wng + bng); s2 = skw + gw*hw2
    #pragma unroll
    for (int i = 0; i < 2; ++i) {
        int oidx = i * 256 + t;
        int tt = oidx >> 6, vv = oidx & 63;
        float acc = bng[vv];
        #pragma unroll
        for (int k4 = 0; k4 < 16; ++k4) {
            float4 h = *(const float4*)&hw2_s[tt][k4 * 4];
            acc += h.x * Wng[(k4*4+0)*64+vv] + h.y * Wng[(k4*4+1)*64+vv]
                 + h.z * Wng[(k4*4+2)*64+vv] + h.w * Wng[(k4*4+3)*64+vv];
        }
        float gw = sigm_f(acc);
        s2_s[tt][vv] = skw_s[tt][vv] + gw * hw2_s[tt][vv];
    }
    __syncthreads();

    // ---- LN over v + softmax; 16 lanes per token
    if (t < 128) {
        int tt = t >> 4, l = t & 15;
        float z[4]; float sum = 0.f, sq = 0.f;
        #pragma unroll
        for (int i = 0; i < 4; ++i) { z[i] = s2_s[tt][l + 16 * i]; sum += z[i]; sq += z[i] * z[i]; }
        #pragma unroll
        for (int m = 1; m < 16; m <<= 1) { sum += __shfl_xor(sum, m); sq += __shfl_xor(sq, m); }
        float mu  = sum * 0.015625f;
        float var = sq * 0.015625f - mu * mu;
        float rs  = rsqrtf(var + LN_EPS);
        float ln[4]; float mx = -1e30f;
        #pragma unroll
        for (int i = 0; i < 4; ++i) {
            ln[i] = (z[i] - mu) * rs * ngamma[l + 16 * i] + nbeta[l + 16 * i];
            mx = fmaxf(mx, ln[i]);
        }
        #pragma unroll
        for (int m = 1; m < 16; m <<= 1) mx = fmaxf(mx, __shfl_xor(mx, m));
        float es = 0.f; float ev[4];
        #pragma unroll
        for (int i = 0; i < 4; ++i) { ev[i] = __expf(ln[i] - mx); es += ev[i]; }
        #pragma unroll
        for (int m = 1; m < 16; m <<= 1) es += __shfl_xor(es, m);
        float inv = 1.f / es;
        #pragma unroll
        for (int i = 0; i < 4; ++i) w_s[tt][l + 16 * i] = ev[i] * inv;
    }
    __syncthreads();

    // ---- weighted sum, vectorized: wave wv handles tokens {2wv, 2wv+1}
    {
        const int vloc = lane >> 3, d8 = (lane & 7) * 8;
        const short* s0 = (const short*)stb + (size_t)(tok0 + wv * 2) * 4096 + d8;
        const short* s1 = s0 + 4096;
        float acc0[8], acc1[8];
        #pragma unroll
        for (int j = 0; j < 8; ++j) { acc0[j] = 0.f; acc1[j] = 0.f; }
        #pragma unroll
        for (int vc = 0; vc < 8; ++vc) {
            int v = vc * 8 + vloc;
            s8v r0 = *(const s8v*)(s0 + v * 64);
            s8v r1 = *(const s8v*)(s1 + v * 64);
            float w0 = w_s[wv * 2][v], w1 = w_s[wv * 2 + 1][v];
            #pragma unroll
            for (int j = 0; j < 8; ++j) {
                acc0[j] = fmaf(w0, bf16_to_f((unsigned short)r0[j]), acc0[j]);
                acc1[j] = fmaf(w1, bf16_to_f((unsigned short)r1[j]), acc1[j]);
            }
        }
        #pragma unroll
        for (int m = 8; m <= 32; m <<= 1)
            #pragma unroll
            for (int j = 0; j < 8; ++j) {
                acc0[j] += __shfl_xor(acc0[j], m);
                acc1[j] += __shfl_xor(acc1[j], m);
            }
        if (lane < 8) {
            float* op = out + (size_t)(tok0 + wv * 2) * 64 + lane * 8;
            *(float4*)op       = make_float4(acc0[0], acc0[1], acc0[2], acc0[3]);
            *(float4*)(op + 4) = make_float4(acc0[4], acc0[5], acc0[6], acc0[7]);
            op += 64;
            *(float4*)op       = make_float4(acc1[0], acc1[1], acc1[2], acc1[3]);
            *(float4*)(op + 4) = make_float4(acc1[4], acc1[5], acc1[6], acc1[7]);
        }
    }
}

extern "C" void kernel_launch(void* const* d_in, const int* in_sizes, int n_in,
                              void* d_out, int out_size, void* d_ws, size_t ws_size,
                              hipStream_t stream) {
    const float* x     = (const float*)d_in[0];
    const float* W1    = (const float*)d_in[1];
    const float* b1    = (const float*)d_in[2];
    const float* W2    = (const float*)d_in[3];
    const float* b2    = (const float*)d_in[4];
    const float* Wg    = (const float*)d_in[5];
    const float* bg    = (const float*)d_in[6];
    const float* Wsk   = (const float*)d_in[7];
    const float* bsk   = (const float*)d_in[8];
    const float* gamma = (const float*)d_in[9];
    const float* beta  = (const float*)d_in[10];
    const float* Wn1   = (const float*)d_in[11];
    const float* bn1   = (const float*)d_in[12];
    const float* Wn2   = (const float*)d_in[13];
    const float* bn2   = (const float*)d_in[14];
    const float* Wng   = (const float*)d_in[15];
    const float* bng   = (const float*)d_in[16];
    const float* Wns   = (const float*)d_in[17];
    const float* bns   = (const float*)d_in[18];
    const float* ngam  = (const float*)d_in[19];
    const float* nbet  = (const float*)d_in[20];

    char* ws = (char*)d_ws;
    __hip_bfloat16* stb = (__hip_bfloat16*)ws;                   // 64 MiB
    __hip_bfloat16* wct = (__hip_bfloat16*)(ws + (64u << 20));   // 1 MiB
    float* part = (float*)(ws + (65u << 20));                    // 32 MiB (8192 x 8 x 128)
    short* w2b = (short*)(ws + (97u << 20));                     // 512 KiB each
    short* wgb = w2b + 262144;
    float* outp = (float*)d_out;

    vsn_prepack<<<dim3(192), 256, 0, stream>>>(W2, Wg, Wn1, Wns, w2b, wgb, wct);
    vsn_stage1<<<dim3(NTOK / 32, 16), 256, 0, stream>>>(
        x, W1, b1, w2b, wgb, b2, bg, Wsk, bsk, gamma, beta, stb);
    vsn_stage2a<<<dim3(NTOK / 128, KSPLIT), 512, 0, stream>>>(stb, wct, part);
    vsn_stage2b<<<dim3(NTOK / 8), 256, 0, stream>>>(
        stb, part, bn1, Wn2, bn2, Wng, bng, bns, ngam, nbet, outp);
}

// Round 11
// 227.273 us; speedup vs baseline: 1.3835x; 1.0052x over previous
//
#include <hip/hip_runtime.h>
#include <hip/hip_bf16.h>
#include <math.h>

#define NV 64
#define ND 64
#define NTOK 8192
#define LN_EPS 1e-5f
#define KSPLIT 8
#define KRANGE (4096 / KSPLIT)   // 512

typedef __attribute__((ext_vector_type(8))) short s8v;    // 8 bf16 = 4 VGPR
typedef __attribute__((ext_vector_type(4))) float f4v;    // MFMA C/D
typedef __attribute__((ext_vector_type(4))) int   i4v;

__device__ __forceinline__ float sigm_f(float x) { return 1.f / (1.f + __expf(-x)); }
__device__ __forceinline__ float elu_f(float x)  { return x > 0.f ? x : (__expf(x) - 1.f); }

__device__ __forceinline__ float bf16_to_f(unsigned short s) {
    union { unsigned int u; float f; } c; c.u = ((unsigned int)s) << 16;
    return c.f;
}
// 1-op round-to-nearest (ties away)
__device__ __forceinline__ unsigned short bf16_rn(float f) {
    union { float f; unsigned int u; } c; c.f = f;
    return (unsigned short)((c.u + 0x8000u) >> 16);
}

// ---------------- Prepack: all weight transposes via LDS tiles (coalesced R+W)
// [round-7 verified]
__global__ __launch_bounds__(256) void vsn_prepack(
    const float* __restrict__ W2, const float* __restrict__ Wg,
    const float* __restrict__ Wn1, const float* __restrict__ Wns,
    short* __restrict__ w2b, short* __restrict__ wgb,
    __hip_bfloat16* __restrict__ wct)
{
    __shared__ float T[64][65];
    const int b = blockIdx.x, t = threadIdx.x;

    if (b < 64) {
        const float* src = W2 + (size_t)b * 4096;
        short* dst = w2b + (size_t)b * 4096;
        #pragma unroll
        for (int pass = 0; pass < 2; ++pass) {
            #pragma unroll
            for (int i = 0; i < 16; ++i) {
                int id = i * 256 + t;
                T[id & 63][id >> 6] = src[id];
            }
            __syncthreads();
            #pragma unroll
            for (int i = 0; i < 16; ++i) {
                int id = i * 256 + t;
                dst[id] = (short)bf16_rn(T[id >> 6][id & 63]);
            }
            __syncthreads();
            src = Wg + (size_t)b * 4096;
            dst = wgb + (size_t)b * 4096;
        }
    } else {
        int tb = b - 64;
        int half = tb >> 6, kt = tb & 63;
        const float* src = (half == 0 ? Wn1 : Wns) + (size_t)(kt * 64) * 64;
        #pragma unroll
        for (int i = 0; i < 16; ++i) {
            int id = i * 256 + t;
            T[id & 63][id >> 6] = src[id];
        }
        __syncthreads();
        #pragma unroll
        for (int i = 0; i < 16; ++i) {
            int id = i * 256 + t;
            int n = id >> 6, r = id & 63;
            wct[(size_t)(half * 64 + n) * 4096 + kt * 64 + r] =
                __float2bfloat16(T[n][r]);
        }
    }
}

// ---------------- Stage 1: per-variable GRN + LN via bf16 MFMA -> stacked bf16
// [round-7 verified, absmax 5.86e-3; unchanged]
__global__ __launch_bounds__(256) void vsn_stage1(
    const float* __restrict__ x,
    const float* __restrict__ W1, const float* __restrict__ b1,
    const short* __restrict__ w2b, const short* __restrict__ wgb,
    const float* __restrict__ b2, const float* __restrict__ bg,
    const float* __restrict__ Wsk, const float* __restrict__ bsk,
    const float* __restrict__ gamma, const float* __restrict__ beta,
    __hip_bfloat16* __restrict__ stb)
{
    const int t = threadIdx.x;
    const int wave = t >> 6, lane = t & 63;
    const int m16 = lane & 15, quad = lane >> 4;
    const int tile0 = blockIdx.x * 32;
    const int v = blockIdx.y * 4 + wave;

    __shared__ float xs[4][32];
    __shared__ __align__(16) unsigned short h2s[4][32][72];

    if (lane < 32) xs[wave][lane] = x[(size_t)(tile0 + lane) * NV + v];

    s8v a[2][2];
    #pragma unroll
    for (int kt = 0; kt < 2; ++kt) {
        float w1k[8], b1k[8];
        *(float4*)&w1k[0] = *(const float4*)(W1 + v * 64 + kt * 32 + quad * 8);
        *(float4*)&w1k[4] = *(const float4*)(W1 + v * 64 + kt * 32 + quad * 8 + 4);
        *(float4*)&b1k[0] = *(const float4*)(b1 + v * 64 + kt * 32 + quad * 8);
        *(float4*)&b1k[4] = *(const float4*)(b1 + v * 64 + kt * 32 + quad * 8 + 4);
        #pragma unroll
        for (int mi = 0; mi < 2; ++mi) {
            float xv = xs[wave][mi * 16 + m16];
            float h[8];
            #pragma unroll
            for (int j = 0; j < 8; ++j) h[j] = elu_f(fmaf(xv, w1k[j], b1k[j]));
            i4v av;
            #pragma unroll
            for (int p = 0; p < 4; ++p) {
                unsigned int u0 = __float_as_uint(h[2 * p]);
                unsigned int u1 = __float_as_uint(h[2 * p + 1]);
                av[p] = (int)((u1 & 0xffff0000u) | (u0 >> 16));
            }
            a[mi][kt] = *(s8v*)&av;
        }
    }

    f4v hacc[2][4];
    #pragma unroll
    for (int mi = 0; mi < 2; ++mi)
        #pragma unroll
        for (int ni = 0; ni < 4; ++ni) hacc[mi][ni] = (f4v){0.f, 0.f, 0.f, 0.f};

    const size_t wb = (size_t)v * 4096;
    #pragma unroll
    for (int ni = 0; ni < 4; ++ni)
        #pragma unroll
        for (int kt = 0; kt < 2; ++kt) {
            s8v bh = *(const s8v*)(w2b + wb + (size_t)(ni * 16 + m16) * 64 + kt * 32 + quad * 8);
            #pragma unroll
            for (int mi = 0; mi < 2; ++mi)
                hacc[mi][ni] = __builtin_amdgcn_mfma_f32_16x16x32_bf16(a[mi][kt], bh, hacc[mi][ni], 0, 0, 0);
        }
    {
        float b2d[4];
        #pragma unroll
        for (int ni = 0; ni < 4; ++ni) b2d[ni] = b2[v * 64 + ni * 16 + m16];
        #pragma unroll
        for (int mi = 0; mi < 2; ++mi)
            #pragma unroll
            for (int ni = 0; ni < 4; ++ni)
                #pragma unroll
                for (int r = 0; r < 4; ++r) hacc[mi][ni][r] += b2d[ni];
    }

    #pragma unroll
    for (int mi = 0; mi < 2; ++mi)
        #pragma unroll
        for (int ni = 0; ni < 4; ++ni)
            #pragma unroll
            for (int r = 0; r < 4; ++r)
                h2s[wave][mi * 16 + quad * 4 + r][ni * 16 + m16] =
                    (unsigned short)(__float_as_uint(hacc[mi][ni][r]) >> 16);

    s8v c[2][2];
    #pragma unroll
    for (int mi = 0; mi < 2; ++mi)
        #pragma unroll
        for (int kt = 0; kt < 2; ++kt)
            c[mi][kt] = *(const s8v*)&h2s[wave][mi * 16 + m16][kt * 32 + quad * 8];

    f4v gacc[2][4];
    #pragma unroll
    for (int mi = 0; mi < 2; ++mi)
        #pragma unroll
        for (int ni = 0; ni < 4; ++ni) gacc[mi][ni] = (f4v){0.f, 0.f, 0.f, 0.f};
    #pragma unroll
    for (int ni = 0; ni < 4; ++ni)
        #pragma unroll
        for (int kt = 0; kt < 2; ++kt) {
            s8v bh = *(const s8v*)(wgb + wb + (size_t)(ni * 16 + m16) * 64 + kt * 32 + quad * 8);
            #pragma unroll
            for (int mi = 0; mi < 2; ++mi)
                gacc[mi][ni] = __builtin_amdgcn_mfma_f32_16x16x32_bf16(c[mi][kt], bh, gacc[mi][ni], 0, 0, 0);
        }

    {
        float bgd[4], wskd[4], bskd[4];
        #pragma unroll
        for (int ni = 0; ni < 4; ++ni) {
            int d = v * 64 + ni * 16 + m16;
            bgd[ni] = bg[d]; wskd[ni] = Wsk[d]; bskd[ni] = bsk[d];
        }
        float xtok[2][4];
        #pragma unroll
        for (int mi = 0; mi < 2; ++mi)
            #pragma unroll
            for (int r = 0; r < 4; ++r) xtok[mi][r] = xs[wave][mi * 16 + quad * 4 + r];
        #pragma unroll
        for (int mi = 0; mi < 2; ++mi)
            #pragma unroll
            for (int ni = 0; ni < 4; ++ni)
                #pragma unroll
                for (int r = 0; r < 4; ++r) {
                    float g = sigm_f(gacc[mi][ni][r] + bgd[ni]);
                    gacc[mi][ni][r] = fmaf(xtok[mi][r], wskd[ni], bskd[ni]) + g * hacc[mi][ni][r];
                }
    }

    {
        float gamd[4], betd[4];
        #pragma unroll
        for (int ni = 0; ni < 4; ++ni) {
            int d = v * 64 + ni * 16 + m16;
            gamd[ni] = gamma[d]; betd[ni] = beta[d];
        }
        #pragma unroll
        for (int mi = 0; mi < 2; ++mi)
            #pragma unroll
            for (int r = 0; r < 4; ++r) {
                float s0 = gacc[mi][0][r], s1 = gacc[mi][1][r], s2 = gacc[mi][2][r], s3 = gacc[mi][3][r];
                float sum = s0 + s1 + s2 + s3;
                float sq  = s0 * s0 + s1 * s1 + s2 * s2 + s3 * s3;
                #pragma unroll
                for (int m = 1; m < 16; m <<= 1) { sum += __shfl_xor(sum, m); sq += __shfl_xor(sq, m); }
                float mu  = sum * 0.015625f;
                float var = sq * 0.015625f - mu * mu;
                float rs  = rsqrtf(var + LN_EPS);
                size_t base = (size_t)(tile0 + mi * 16 + quad * 4 + r) * 4096 + (size_t)v * 64 + m16;
                #pragma unroll
                for (int ni = 0; ni < 4; ++ni)
                    stb[base + ni * 16] = __hip_bfloat16_raw{
                        bf16_rn((gacc[mi][ni][r] - mu) * rs * gamd[ni] + betd[ni])};
            }
    }
}

// ---------------- Stage 2a: part[tok][s][0:128] = flat @ [Wn1|Wns] over K-range s
// Depth-2 register-prefetch pipeline (AITER-style: vmcnt waits never drain).
// 512-thread blocks: 128 tokens (2 M-tiles x 4 n-waves); grid (64, KSPLIT).
__global__ __launch_bounds__(512) void vsn_stage2a(
    const __hip_bfloat16* __restrict__ stb,   // [8192][4096]
    const __hip_bfloat16* __restrict__ wct,   // [128][4096]
    float* __restrict__ part)                 // [8192][KSPLIT][128]
{
    const int t = threadIdx.x;
    const int wave = t >> 6, lane = t & 63;
    const int mtile = wave >> 2;
    const int n0 = (wave & 3) * 32;
    const int tok0 = blockIdx.x * 128 + mtile * 64;
    const int s = blockIdx.y;
    const int k0 = s * KRANGE;
    const int m16 = lane & 15, quad = lane >> 4;

    const short* A  = (const short*)stb;
    const short* Bw = (const short*)wct;

    f4v acc[4][2];
    #pragma unroll
    for (int i = 0; i < 4; ++i)
        #pragma unroll
        for (int j = 0; j < 2; ++j)
            acc[i][j] = (f4v){0.f, 0.f, 0.f, 0.f};

    const short* arow = A  + (size_t)(tok0 + m16) * 4096 + quad * 8;
    const short* brow = Bw + (size_t)(n0 + m16) * 4096 + quad * 8;

    // 3 rotating register stages; loads for iter it+2 issue before MFMAs of it.
    s8v abuf[3][4], bbuf[3][2];
    #pragma unroll
    for (int st = 0; st < 2; ++st) {
        int k = k0 + st * 32;
        #pragma unroll
        for (int i = 0; i < 4; ++i)
            abuf[st][i] = *(const s8v*)(arow + (size_t)i * 16 * 4096 + k);
        #pragma unroll
        for (int j = 0; j < 2; ++j)
            bbuf[st][j] = *(const s8v*)(brow + (size_t)j * 16 * 4096 + k);
    }

    #pragma unroll
    for (int it = 0; it < 16; ++it) {
        if (it < 14) {
            const int st = (it + 2) % 3;
            const int k = k0 + (it + 2) * 32;
            #pragma unroll
            for (int i = 0; i < 4; ++i)
                abuf[st][i] = *(const s8v*)(arow + (size_t)i * 16 * 4096 + k);
            #pragma unroll
            for (int j = 0; j < 2; ++j)
                bbuf[st][j] = *(const s8v*)(brow + (size_t)j * 16 * 4096 + k);
        }
        const int cs = it % 3;
        #pragma unroll
        for (int i = 0; i < 4; ++i)
            #pragma unroll
            for (int j = 0; j < 2; ++j)
                acc[i][j] = __builtin_amdgcn_mfma_f32_16x16x32_bf16(
                    abuf[cs][i], bbuf[cs][j], acc[i][j], 0, 0, 0);
    }

    #pragma unroll
    for (int i = 0; i < 4; ++i)
        #pragma unroll
        for (int j = 0; j < 2; ++j)
            #pragma unroll
            for (int r = 0; r < 4; ++r)
                part[((size_t)(tok0 + i * 16 + quad * 4 + r)) * (KSPLIT * 128)
                     + s * 128 + n0 + j * 16 + m16] = acc[i][j][r];
}

// ---------------- Stage 2b: contiguous part reduce, tail GRN, softmax, weighted sum
// stb loads for the weighted sum are HOISTED above LN/softmax (they don't depend
// on the weights) so ~500 cyc of shuffle/exp work hides their latency.
// 8 tokens per block -> 1024 blocks, 256 threads (4 waves; wave = 2 tokens).
__global__ __launch_bounds__(256) void vsn_stage2b(
    const __hip_bfloat16* __restrict__ stb, const float* __restrict__ part,
    const float* __restrict__ bn1,
    const float* __restrict__ Wn2, const float* __restrict__ bn2,
    const float* __restrict__ Wng, const float* __restrict__ bng,
    const float* __restrict__ bns,
    const float* __restrict__ ngamma, const float* __restrict__ nbeta,
    float* __restrict__ out)
{
    const int t = threadIdx.x;
    const int tok0 = blockIdx.x * 8;
    const int lane = t & 63, wv = t >> 6;

    __shared__ __align__(16) float hw1_s[8][64];
    __shared__ __align__(16) float skw_s[8][64];
    __shared__ __align__(16) float hw2_s[8][64];
    __shared__ float s2_s[8][64];
    __shared__ float w_s[8][64];

    // ---- phase 1: reduce part[tok][0:8][0:128] with contiguous f4 wave-loads.
    #pragma unroll
    for (int tk = 0; tk < 2; ++tk) {
        int tl = wv * 2 + tk;
        const float* pr = part + (size_t)(tok0 + tl) * (KSPLIT * 128)
                        + (lane >> 5) * 128 + (lane & 31) * 4;
        float4 a0 = *(const float4*)(pr);
        float4 a1 = *(const float4*)(pr + 256);
        float4 a2 = *(const float4*)(pr + 512);
        float4 a3 = *(const float4*)(pr + 768);
        float tv[4];
        tv[0] = a0.x + a1.x + a2.x + a3.x;
        tv[1] = a0.y + a1.y + a2.y + a3.y;
        tv[2] = a0.z + a1.z + a2.z + a3.z;
        tv[3] = a0.w + a1.w + a2.w + a3.w;
        #pragma unroll
        for (int c = 0; c < 4; ++c) tv[c] += __shfl_xor(tv[c], 32);
        if (lane < 16) {
            int j0 = lane * 4;
            float4 bb = *(const float4*)(bn1 + j0);
            hw1_s[tl][j0 + 0] = elu_f(tv[0] + bb.x);
            hw1_s[tl][j0 + 1] = elu_f(tv[1] + bb.y);
            hw1_s[tl][j0 + 2] = elu_f(tv[2] + bb.z);
            hw1_s[tl][j0 + 3] = elu_f(tv[3] + bb.w);
        } else if (lane < 32) {
            int j0 = (lane - 16) * 4;
            float4 bb = *(const float4*)(bns + j0);
            skw_s[tl][j0 + 0] = tv[0] + bb.x;
            skw_s[tl][j0 + 1] = tv[1] + bb.y;
            skw_s[tl][j0 + 2] = tv[2] + bb.z;
            skw_s[tl][j0 + 3] = tv[3] + bb.w;
        }
    }
    __syncthreads();

    // ---- hw2 = hw1 @ Wn2 + bn2
    #pragma unroll
    for (int i = 0; i < 2; ++i) {
        int oidx = i * 256 + t;
        int tt = oidx >> 6, jj = oidx & 63;
        float acc = bn2[jj];
        #pragma unroll
        for (int k4 = 0; k4 < 16; ++k4) {
            float4 h = *(const float4*)&hw1_s[tt][k4 * 4];
            acc += h.x * Wn2[(k4*4+0)*64+jj] + h.y * Wn2[(k4*4+1)*64+jj]
                 + h.z * Wn2[(k4*4+2)*64+jj] + h.w * Wn2[(k4*4+3)*64+jj];
        }
        hw2_s[tt][jj] = acc;
    }
    __syncthreads();

    // ---- gw = sigmoid(hw2 @ Wng + bng); s2 = skw + gw*hw2
    #pragma unroll
    for (int i = 0; i < 2; ++i) {
        int oidx = i * 256 + t;
        int tt = oidx >> 6, vv = oidx & 63;
        float acc = bng[vv];
        #pragma unroll
        for (int k4 = 0; k4 < 16; ++k4) {
            float4 h = *(const float4*)&hw2_s[tt][k4 * 4];
            acc += h.x * Wng[(k4*4+0)*64+vv] + h.y * Wng[(k4*4+1)*64+vv]
                 + h.z * Wng[(k4*4+2)*64+vv] + h.w * Wng[(k4*4+3)*64+vv];
        }
        float gw = sigm_f(acc);
        s2_s[tt][vv] = skw_s[tt][vv] + gw * hw2_s[tt][vv];
    }
    __syncthreads();

    // ---- HOISTED stb loads for the weighted sum (independent of softmax)
    const int vloc = lane >> 3, d8 = (lane & 7) * 8;
    s8v r0[8], r1[8];
    {
        const short* s0 = (const short*)stb + (size_t)(tok0 + wv * 2) * 4096 + d8;
        const short* s1 = s0 + 4096;
        #pragma unroll
        for (int vc = 0; vc < 8; ++vc) {
            r0[vc] = *(const s8v*)(s0 + (vc * 8 + vloc) * 64);
            r1[vc] = *(const s8v*)(s1 + (vc * 8 + vloc) * 64);
        }
    }

    // ---- LN over v + softmax; 16 lanes per token
    if (t < 128) {
        int tt = t >> 4, l = t & 15;
        float z[4]; float sum = 0.f, sq = 0.f;
        #pragma unroll
        for (int i = 0; i < 4; ++i) { z[i] = s2_s[tt][l + 16 * i]; sum += z[i]; sq += z[i] * z[i]; }
        #pragma unroll
        for (int m = 1; m < 16; m <<= 1) { sum += __shfl_xor(sum, m); sq += __shfl_xor(sq, m); }
        float mu  = sum * 0.015625f;
        float var = sq * 0.015625f - mu * mu;
        float rs  = rsqrtf(var + LN_EPS);
        float ln[4]; float mx = -1e30f;
        #pragma unroll
        for (int i = 0; i < 4; ++i) {
            ln[i] = (z[i] - mu) * rs * ngamma[l + 16 * i] + nbeta[l + 16 * i];
            mx = fmaxf(mx, ln[i]);
        }
        #pragma unroll
        for (int m = 1; m < 16; m <<= 1) mx = fmaxf(mx, __shfl_xor(mx, m));
        float es = 0.f; float ev[4];
        #pragma unroll
        for (int i = 0; i < 4; ++i) { ev[i] = __expf(ln[i] - mx); es += ev[i]; }
        #pragma unroll
        for (int m = 1; m < 16; m <<= 1) es += __shfl_xor(es, m);
        float inv = 1.f / es;
        #pragma unroll
        for (int i = 0; i < 4; ++i) w_s[tt][l + 16 * i] = ev[i] * inv;
    }
    __syncthreads();

    // ---- weighted sum from the hoisted registers
    {
        float acc0[8], acc1[8];
        #pragma unroll
        for (int j = 0; j < 8; ++j) { acc0[j] = 0.f; acc1[j] = 0.f; }
        #pragma unroll
        for (int vc = 0; vc < 8; ++vc) {
            int v = vc * 8 + vloc;
            float w0 = w_s[wv * 2][v], w1 = w_s[wv * 2 + 1][v];
            #pragma unroll
            for (int j = 0; j < 8; ++j) {
                acc0[j] = fmaf(w0, bf16_to_f((unsigned short)r0[vc][j]), acc0[j]);
                acc1[j] = fmaf(w1, bf16_to_f((unsigned short)r1[vc][j]), acc1[j]);
            }
        }
        #pragma unroll
        for (int m = 8; m <= 32; m <<= 1)
            #pragma unroll
            for (int j = 0; j < 8; ++j) {
                acc0[j] += __shfl_xor(acc0[j], m);
                acc1[j] += __shfl_xor(acc1[j], m);
            }
        if (lane < 8) {
            float* op = out + (size_t)(tok0 + wv * 2) * 64 + lane * 8;
            *(float4*)op       = make_float4(acc0[0], acc0[1], acc0[2], acc0[3]);
            *(float4*)(op + 4) = make_float4(acc0[4], acc0[5], acc0[6], acc0[7]);
            op += 64;
            *(float4*)op       = make_float4(acc1[0], acc1[1], acc1[2], acc1[3]);
            *(float4*)(op + 4) = make_float4(acc1[4], acc1[5], acc1[6], acc1[7]);
        }
    }
}

extern "C" void kernel_launch(void* const* d_in, const int* in_sizes, int n_in,
                              void* d_out, int out_size, void* d_ws, size_t ws_size,
                              hipStream_t stream) {
    const float* x     = (const float*)d_in[0];
    const float* W1    = (const float*)d_in[1];
    const float* b1    = (const float*)d_in[2];
    const float* W2    = (const float*)d_in[3];
    const float* b2    = (const float*)d_in[4];
    const float* Wg    = (const float*)d_in[5];
    const float* bg    = (const float*)d_in[6];
    const float* Wsk   = (const float*)d_in[7];
    const float* bsk   = (const float*)d_in[8];
    const float* gamma = (const float*)d_in[9];
    const float* beta  = (const float*)d_in[10];
    const float* Wn1   = (const float*)d_in[11];
    const float* bn1   = (const float*)d_in[12];
    const float* Wn2   = (const float*)d_in[13];
    const float* bn2   = (const float*)d_in[14];
    const float* Wng   = (const float*)d_in[15];
    const float* bng   = (const float*)d_in[16];
    const float* Wns   = (const float*)d_in[17];
    const float* bns   = (const float*)d_in[18];
    const float* ngam  = (const float*)d_in[19];
    const float* nbet  = (const float*)d_in[20];

    char* ws = (char*)d_ws;
    __hip_bfloat16* stb = (__hip_bfloat16*)ws;                   // 64 MiB
    __hip_bfloat16* wct = (__hip_bfloat16*)(ws + (64u << 20));   // 1 MiB
    float* part = (float*)(ws + (65u << 20));                    // 32 MiB (8192 x 8 x 128)
    short* w2b = (short*)(ws + (97u << 20));                     // 512 KiB each
    short* wgb = w2b + 262144;
    float* outp = (float*)d_out;

    vsn_prepack<<<dim3(192), 256, 0, stream>>>(W2, Wg, Wn1, Wns, w2b, wgb, wct);
    vsn_stage1<<<dim3(NTOK / 32, 16), 256, 0, stream>>>(
        x, W1, b1, w2b, wgb, b2, bg, Wsk, bsk, gamma, beta, stb);
    vsn_stage2a<<<dim3(NTOK / 128, KSPLIT), 512, 0, stream>>>(stb, wct, part);
    vsn_stage2b<<<dim3(NTOK / 8), 256, 0, stream>>>(
        stb, part, bn1, Wn2, bn2, Wng, bng, bns, ngam, nbet, outp);
}